// Round 1
// baseline (260.894 us; speedup 1.0000x reference)
//
#include <hip/hip_runtime.h>
#include <math.h>

#define Wd 512
#define Hd 512
#define Bd 32
#define PLANE (Hd * Wd)

__device__ __forceinline__ float clip01(float x) { return fminf(fmaxf(x, 0.f), 1.f); }

// Bilinear sample 3 image planes + 1 mask plane of batch b at (sx,sy) with
// zeros padding, with optional h/v flip folded into the gather indices
// (sampling the flipped image at (x,y) == sampling original at flipped idx).
__device__ __forceinline__ void bilin4(const float* __restrict__ ib,   // img batch base (plane 0)
                                       const float* __restrict__ mb,   // mask plane base
                                       float sx, float sy, bool hf, bool vf,
                                       float& r, float& g, float& b2, float& m)
{
    float x0f = floorf(sx), y0f = floorf(sy);
    float wx = sx - x0f, wy = sy - y0f;
    float w00 = (1.f - wx) * (1.f - wy);
    float w10 = wx * (1.f - wy);
    float w01 = (1.f - wx) * wy;
    float w11 = wx * wy;
    bool vx0 = (x0f >= 0.f) && (x0f <= (float)(Wd - 1));
    bool vx1 = (x0f + 1.f >= 0.f) && (x0f + 1.f <= (float)(Wd - 1));
    bool vy0 = (y0f >= 0.f) && (y0f <= (float)(Hd - 1));
    bool vy1 = (y0f + 1.f >= 0.f) && (y0f + 1.f <= (float)(Hd - 1));
    if (!(vx0 && vy0)) w00 = 0.f;
    if (!(vx1 && vy0)) w10 = 0.f;
    if (!(vx0 && vy1)) w01 = 0.f;
    if (!(vx1 && vy1)) w11 = 0.f;
    int x0 = (int)x0f, y0 = (int)y0f;
    int xc0 = min(max(x0, 0), Wd - 1), xc1 = min(max(x0 + 1, 0), Wd - 1);
    int yc0 = min(max(y0, 0), Hd - 1), yc1 = min(max(y0 + 1, 0), Hd - 1);
    if (hf) { xc0 = Wd - 1 - xc0; xc1 = Wd - 1 - xc1; }
    if (vf) { yc0 = Hd - 1 - yc0; yc1 = Hd - 1 - yc1; }
    int i00 = yc0 * Wd + xc0, i10 = yc0 * Wd + xc1;
    int i01 = yc1 * Wd + xc0, i11 = yc1 * Wd + xc1;

    r  = w00 * ib[i00]             + w10 * ib[i10]             + w01 * ib[i01]             + w11 * ib[i11];
    g  = w00 * ib[i00 + PLANE]     + w10 * ib[i10 + PLANE]     + w01 * ib[i01 + PLANE]     + w11 * ib[i11 + PLANE];
    b2 = w00 * ib[i00 + 2*PLANE]   + w10 * ib[i10 + 2*PLANE]   + w01 * ib[i01 + 2*PLANE]   + w11 * ib[i11 + 2*PLANE];
    m  = w00 * mb[i00]             + w10 * mb[i10]             + w01 * mb[i01]             + w11 * mb[i11];
}

// K1: flip(+) rotate -> ws intermediates
__global__ __launch_bounds__(256) void k_rotate(const float* __restrict__ imgs,
                                                const float* __restrict__ masks,
                                                const int* __restrict__ hflip,
                                                const int* __restrict__ vflip,
                                                const float* __restrict__ angles,
                                                float* __restrict__ rimgs,
                                                float* __restrict__ rmasks)
{
    int x = blockIdx.x * 32 + threadIdx.x;
    int y = blockIdx.y * 8 + threadIdx.y;
    int b = blockIdx.z;
    const float cx = (Wd - 1) * 0.5f, cy = (Hd - 1) * 0.5f;
    float th = angles[b] * 0.017453292519943295f;
    float c = cosf(th), s = sinf(th);
    float dx = (float)x - cx, dy = (float)y - cy;
    float sx = c * dx + s * dy + cx;
    float sy = -s * dx + c * dy + cy;
    bool hf = hflip[b] > 0, vf = vflip[b] > 0;

    const float* ib = imgs + (size_t)b * 3 * PLANE;
    const float* mb = masks + (size_t)b * PLANE;
    float r, g, b2, m;
    bilin4(ib, mb, sx, sy, hf, vf, r, g, b2, m);

    size_t po = (size_t)b * 3 * PLANE + (size_t)y * Wd + x;
    rimgs[po] = r;
    rimgs[po + PLANE] = g;
    rimgs[po + 2 * PLANE] = b2;
    rmasks[(size_t)b * PLANE + (size_t)y * Wd + x] = m;
}

// K2: affine sample from ws -> d_out; brightness clip on imgs; per-block gray partial sums
__global__ __launch_bounds__(256) void k_affine(const float* __restrict__ rimgs,
                                                const float* __restrict__ rmasks,
                                                const float* __restrict__ translate,
                                                const float* __restrict__ scale,
                                                const float* __restrict__ brightness,
                                                float* __restrict__ oimgs,
                                                float* __restrict__ omasks,
                                                float* __restrict__ partials)
{
    int x = blockIdx.x * 32 + threadIdx.x;
    int y = blockIdx.y * 8 + threadIdx.y;
    int b = blockIdx.z;
    const float cx = (Wd - 1) * 0.5f, cy = (Hd - 1) * 0.5f;
    float tx = translate[2 * b] * (float)Wd;
    float ty = translate[2 * b + 1] * (float)Hd;
    float sc = scale[b];
    float sx = ((float)x - cx - tx) / sc + cx;
    float sy = ((float)y - cy - ty) / sc + cy;

    const float* ib = rimgs + (size_t)b * 3 * PLANE;
    const float* mb = rmasks + (size_t)b * PLANE;
    float r, g, b2, m;
    bilin4(ib, mb, sx, sy, false, false, r, g, b2, m);

    float bf = brightness[b];
    r = clip01(r * bf);
    g = clip01(g * bf);
    b2 = clip01(b2 * bf);

    size_t po = (size_t)b * 3 * PLANE + (size_t)y * Wd + x;
    oimgs[po] = r;
    oimgs[po + PLANE] = g;
    oimgs[po + 2 * PLANE] = b2;
    omasks[(size_t)b * PLANE + (size_t)y * Wd + x] = m;

    // deterministic per-block reduction of post-brightness gray
    float gray = 0.299f * r + 0.587f * g + 0.114f * b2;
    __shared__ float sred[256];
    int tid = threadIdx.y * 32 + threadIdx.x;
    sred[tid] = gray;
    __syncthreads();
    for (int off = 128; off > 0; off >>= 1) {
        if (tid < off) sred[tid] += sred[tid + off];
        __syncthreads();
    }
    if (tid == 0)
        partials[(size_t)b * 1024 + (size_t)blockIdx.y * gridDim.x + blockIdx.x] = sred[0];
}

// K2b: reduce 1024 partials per image -> mean
__global__ __launch_bounds__(256) void k_mean(const float* __restrict__ partials,
                                              float* __restrict__ means)
{
    int b = blockIdx.x;
    int t = threadIdx.x;
    float s = partials[(size_t)b * 1024 + t]
            + partials[(size_t)b * 1024 + t + 256]
            + partials[(size_t)b * 1024 + t + 512]
            + partials[(size_t)b * 1024 + t + 768];
    __shared__ float sr[256];
    sr[t] = s;
    __syncthreads();
    for (int off = 128; off > 0; off >>= 1) {
        if (t < off) sr[t] += sr[t + off];
        __syncthreads();
    }
    if (t == 0) means[b] = sr[0] * (1.f / (float)PLANE);
}

// K3: contrast -> saturation -> hue, in-place on d_out imgs region
__global__ __launch_bounds__(256) void k_jitter(float* __restrict__ oimgs,
                                                const float* __restrict__ means,
                                                const float* __restrict__ contrast,
                                                const float* __restrict__ saturation,
                                                const float* __restrict__ hue)
{
    int x = blockIdx.x * 32 + threadIdx.x;
    int y = blockIdx.y * 8 + threadIdx.y;
    int b = blockIdx.z;
    size_t po = (size_t)b * 3 * PLANE + (size_t)y * Wd + x;
    float r = oimgs[po];
    float g = oimgs[po + PLANE];
    float bl = oimgs[po + 2 * PLANE];

    float mean = means[b];
    float cf = contrast[b];
    float sf = saturation[b];
    float hshift = hue[b];

    // contrast
    r = clip01(cf * r + (1.f - cf) * mean);
    g = clip01(cf * g + (1.f - cf) * mean);
    bl = clip01(cf * bl + (1.f - cf) * mean);
    // saturation
    float gray = 0.299f * r + 0.587f * g + 0.114f * bl;
    r = clip01(sf * r + (1.f - sf) * gray);
    g = clip01(sf * g + (1.f - sf) * gray);
    bl = clip01(sf * bl + (1.f - sf) * gray);

    // rgb -> hsv
    float maxc = fmaxf(fmaxf(r, g), bl);
    float minc = fminf(fminf(r, g), bl);
    float delta = maxc - minc;
    float s = delta / (maxc + 1e-8f);
    float dd = delta + 1e-8f;
    float rc = (maxc - r) / dd;
    float gc = (maxc - g) / dd;
    float bc = (maxc - bl) / dd;
    float h6 = (maxc == r) ? (bc - gc) : ((maxc == g) ? (2.f + rc - bc) : (4.f + gc - rc));
    float h = h6 * (1.f / 6.f);
    h = h - floorf(h);          // python % 1.0
    h = h + hshift;
    h = h - floorf(h);

    // hsv -> rgb
    float hi = floorf(h * 6.f);
    float f = h * 6.f - hi;
    float v = maxc;
    float p = v * (1.f - s);
    float q = v * (1.f - f * s);
    float t = v * (1.f - (1.f - f) * s);
    int i = ((int)hi) % 6;
    if (i < 0) i += 6;
    float rr, gg, bb;
    switch (i) {
        case 0: rr = v; gg = t; bb = p; break;
        case 1: rr = q; gg = v; bb = p; break;
        case 2: rr = p; gg = v; bb = t; break;
        case 3: rr = p; gg = q; bb = v; break;
        case 4: rr = t; gg = p; bb = v; break;
        default: rr = v; gg = p; bb = q; break;
    }

    oimgs[po] = clip01(rr);
    oimgs[po + PLANE] = clip01(gg);
    oimgs[po + 2 * PLANE] = clip01(bb);
}

extern "C" void kernel_launch(void* const* d_in, const int* in_sizes, int n_in,
                              void* d_out, int out_size, void* d_ws, size_t ws_size,
                              hipStream_t stream)
{
    const float* imgs       = (const float*)d_in[0];
    const float* masks      = (const float*)d_in[1];
    const int*   hflip      = (const int*)d_in[2];
    const int*   vflip      = (const int*)d_in[3];
    const float* angles     = (const float*)d_in[4];
    const float* translate  = (const float*)d_in[5];
    const float* scale      = (const float*)d_in[6];
    const float* brightness = (const float*)d_in[7];
    const float* contrast   = (const float*)d_in[8];
    const float* saturation = (const float*)d_in[9];
    const float* hue        = (const float*)d_in[10];

    float* oimgs  = (float*)d_out;                       // [32,3,512,512]
    float* omasks = oimgs + (size_t)Bd * 3 * PLANE;      // [32,1,512,512]

    float* ws       = (float*)d_ws;
    float* rimgs    = ws;                                 // 32*3*PLANE
    float* rmasks   = rimgs + (size_t)Bd * 3 * PLANE;     // 32*PLANE
    float* partials = rmasks + (size_t)Bd * PLANE;        // 32*1024
    float* means    = partials + Bd * 1024;               // 32

    dim3 blk(32, 8);
    dim3 grd(Wd / 32, Hd / 8, Bd);

    k_rotate<<<grd, blk, 0, stream>>>(imgs, masks, hflip, vflip, angles, rimgs, rmasks);
    k_affine<<<grd, blk, 0, stream>>>(rimgs, rmasks, translate, scale, brightness,
                                      oimgs, omasks, partials);
    k_mean<<<Bd, 256, 0, stream>>>(partials, means);
    k_jitter<<<grd, blk, 0, stream>>>(oimgs, means, contrast, saturation, hue);
}

// Round 2
// 205.855 us; speedup vs baseline: 1.2674x; 1.2674x over previous
//
#include <hip/hip_runtime.h>
#include <math.h>

#define Wd 512
#define Hd 512
#define Bd 32
#define PLANE (Hd * Wd)

// rotation LDS tile: 36x36 float4 (r,g,b,mask) = 20736 B
#define TBW 36
#define TBH 36

__device__ __forceinline__ float clip01(float x) { return fminf(fmaxf(x, 0.f), 1.f); }

// ---------------------------------------------------------------------------
// K1: flip + rotate, LDS-staged. Each block produces a 32x8 output tile; the
// rotated source bounding box (<=34x34 for any angle, +1 guard ring) is staged
// in LDS as float4{r,g,b,m}, zero-padded outside the image. Zero-padded
// bilinear == reference's validity-masked gather.
// ---------------------------------------------------------------------------
__global__ __launch_bounds__(256) void k_rotate(const float* __restrict__ imgs,
                                                const float* __restrict__ masks,
                                                const int* __restrict__ hflip,
                                                const int* __restrict__ vflip,
                                                const float* __restrict__ angles,
                                                float* __restrict__ rimgs,
                                                float* __restrict__ rmasks)
{
    __shared__ float4 tile[TBH * TBW];

    const int tx = threadIdx.x, ty = threadIdx.y;
    const int bx = blockIdx.x * 32, by = blockIdx.y * 8;
    const int b = blockIdx.z;

    const float cx = (Wd - 1) * 0.5f, cy = (Hd - 1) * 0.5f;
    const float th = angles[b] * 0.017453292519943295f;
    const float c = cosf(th), s = sinf(th);
    const bool hf = hflip[b] > 0, vf = vflip[b] > 0;

    // source coords of the 4 output-tile corners -> bbox
    float dx0 = (float)bx - cx, dx1 = (float)(bx + 31) - cx;
    float dy0 = (float)by - cy, dy1 = (float)(by + 7) - cy;
    float sx00 = c * dx0 + s * dy0, sx10 = c * dx1 + s * dy0;
    float sx01 = c * dx0 + s * dy1, sx11 = c * dx1 + s * dy1;
    float sy00 = -s * dx0 + c * dy0, sy10 = -s * dx1 + c * dy0;
    float sy01 = -s * dx0 + c * dy1, sy11 = -s * dx1 + c * dy1;
    float minsx = fminf(fminf(sx00, sx10), fminf(sx01, sx11)) + cx;
    float maxsx = fmaxf(fmaxf(sx00, sx10), fmaxf(sx01, sx11)) + cx;
    float minsy = fminf(fminf(sy00, sy10), fminf(sy01, sy11)) + cy;
    float maxsy = fmaxf(fmaxf(sy00, sy10), fmaxf(sy01, sy11)) + cy;

    // guard ring of 1 on each side (ULP safety); clamp to LDS budget
    int bx0 = (int)floorf(minsx) - 1;
    int by0 = (int)floorf(minsy) - 1;
    int bw = min((int)floorf(maxsx) + 2 - bx0 + 1, TBW);
    int bh = min((int)floorf(maxsy) + 2 - by0 + 1, TBH);

    const float* ib = imgs + (size_t)b * 3 * PLANE;
    const float* mb = masks + (size_t)b * PLANE;

    // cooperative, coalesced staging (zero outside the image; flip folded in)
    for (int row = ty; row < bh; row += 8) {
        int gy = by0 + row;
        int fy = vf ? (Hd - 1 - gy) : gy;
        bool yin = (unsigned)gy < (unsigned)Hd;
        for (int col = tx; col < bw; col += 32) {
            int gx = bx0 + col;
            float4 v = make_float4(0.f, 0.f, 0.f, 0.f);
            if (yin && (unsigned)gx < (unsigned)Wd) {
                int fx = hf ? (Wd - 1 - gx) : gx;
                int gi = fy * Wd + fx;
                v.x = ib[gi];
                v.y = ib[gi + PLANE];
                v.z = ib[gi + 2 * PLANE];
                v.w = mb[gi];
            }
            tile[row * TBW + col] = v;
        }
    }
    __syncthreads();

    // sample from LDS
    int x = bx + tx, y = by + ty;
    float ddx = (float)x - cx, ddy = (float)y - cy;
    float sx = c * ddx + s * ddy + cx;
    float sy = -s * ddx + c * ddy + cy;
    float sxl = sx - (float)bx0;
    float syl = sy - (float)by0;
    float x0f = floorf(sxl), y0f = floorf(syl);
    float wx = sxl - x0f, wy = syl - y0f;
    int xi = min(max((int)x0f, 0), bw - 2);
    int yi = min(max((int)y0f, 0), bh - 2);

    const float4* p = &tile[yi * TBW + xi];
    float4 v00 = p[0], v10 = p[1], v01 = p[TBW], v11 = p[TBW + 1];
    float w00 = (1.f - wx) * (1.f - wy);
    float w10 = wx * (1.f - wy);
    float w01 = (1.f - wx) * wy;
    float w11 = wx * wy;

    float r  = w00 * v00.x + w10 * v10.x + w01 * v01.x + w11 * v11.x;
    float g  = w00 * v00.y + w10 * v10.y + w01 * v01.y + w11 * v11.y;
    float b2 = w00 * v00.z + w10 * v10.z + w01 * v01.z + w11 * v11.z;
    float m  = w00 * v00.w + w10 * v10.w + w01 * v01.w + w11 * v11.w;

    size_t po = (size_t)b * 3 * PLANE + (size_t)y * Wd + x;
    rimgs[po] = r;
    rimgs[po + PLANE] = g;
    rimgs[po + 2 * PLANE] = b2;
    rmasks[(size_t)b * PLANE + (size_t)y * Wd + x] = m;
}

// ---------------------------------------------------------------------------
// K2: affine sample from ws -> d_out; brightness clip; per-block gray partials
// (affine scale is 0.9..1.1 -> gathers are near-coalesced; no LDS staging)
// ---------------------------------------------------------------------------
__device__ __forceinline__ void bilin4g(const float* __restrict__ ib,
                                        const float* __restrict__ mb,
                                        float sx, float sy,
                                        float& r, float& g, float& b2, float& m)
{
    float x0f = floorf(sx), y0f = floorf(sy);
    float wx = sx - x0f, wy = sy - y0f;
    float w00 = (1.f - wx) * (1.f - wy);
    float w10 = wx * (1.f - wy);
    float w01 = (1.f - wx) * wy;
    float w11 = wx * wy;
    bool vx0 = (x0f >= 0.f) && (x0f <= (float)(Wd - 1));
    bool vx1 = (x0f + 1.f >= 0.f) && (x0f + 1.f <= (float)(Wd - 1));
    bool vy0 = (y0f >= 0.f) && (y0f <= (float)(Hd - 1));
    bool vy1 = (y0f + 1.f >= 0.f) && (y0f + 1.f <= (float)(Hd - 1));
    if (!(vx0 && vy0)) w00 = 0.f;
    if (!(vx1 && vy0)) w10 = 0.f;
    if (!(vx0 && vy1)) w01 = 0.f;
    if (!(vx1 && vy1)) w11 = 0.f;
    int x0 = (int)x0f, y0 = (int)y0f;
    int xc0 = min(max(x0, 0), Wd - 1), xc1 = min(max(x0 + 1, 0), Wd - 1);
    int yc0 = min(max(y0, 0), Hd - 1), yc1 = min(max(y0 + 1, 0), Hd - 1);
    int i00 = yc0 * Wd + xc0, i10 = yc0 * Wd + xc1;
    int i01 = yc1 * Wd + xc0, i11 = yc1 * Wd + xc1;

    r  = w00 * ib[i00]           + w10 * ib[i10]           + w01 * ib[i01]           + w11 * ib[i11];
    g  = w00 * ib[i00 + PLANE]   + w10 * ib[i10 + PLANE]   + w01 * ib[i01 + PLANE]   + w11 * ib[i11 + PLANE];
    b2 = w00 * ib[i00 + 2*PLANE] + w10 * ib[i10 + 2*PLANE] + w01 * ib[i01 + 2*PLANE] + w11 * ib[i11 + 2*PLANE];
    m  = w00 * mb[i00]           + w10 * mb[i10]           + w01 * mb[i01]           + w11 * mb[i11];
}

__global__ __launch_bounds__(256) void k_affine(const float* __restrict__ rimgs,
                                                const float* __restrict__ rmasks,
                                                const float* __restrict__ translate,
                                                const float* __restrict__ scale,
                                                const float* __restrict__ brightness,
                                                float* __restrict__ oimgs,
                                                float* __restrict__ omasks,
                                                float* __restrict__ partials)
{
    int x = blockIdx.x * 32 + threadIdx.x;
    int y = blockIdx.y * 8 + threadIdx.y;
    int b = blockIdx.z;
    const float cx = (Wd - 1) * 0.5f, cy = (Hd - 1) * 0.5f;
    float tx = translate[2 * b] * (float)Wd;
    float ty = translate[2 * b + 1] * (float)Hd;
    float sc = scale[b];
    float sx = ((float)x - cx - tx) / sc + cx;
    float sy = ((float)y - cy - ty) / sc + cy;

    const float* ib = rimgs + (size_t)b * 3 * PLANE;
    const float* mb = rmasks + (size_t)b * PLANE;
    float r, g, b2, m;
    bilin4g(ib, mb, sx, sy, r, g, b2, m);

    float bf = brightness[b];
    r = clip01(r * bf);
    g = clip01(g * bf);
    b2 = clip01(b2 * bf);

    size_t po = (size_t)b * 3 * PLANE + (size_t)y * Wd + x;
    oimgs[po] = r;
    oimgs[po + PLANE] = g;
    oimgs[po + 2 * PLANE] = b2;
    omasks[(size_t)b * PLANE + (size_t)y * Wd + x] = m;

    float gray = 0.299f * r + 0.587f * g + 0.114f * b2;
    __shared__ float sred[256];
    int tid = threadIdx.y * 32 + threadIdx.x;
    sred[tid] = gray;
    __syncthreads();
    for (int off = 128; off > 0; off >>= 1) {
        if (tid < off) sred[tid] += sred[tid + off];
        __syncthreads();
    }
    if (tid == 0)
        partials[(size_t)b * 1024 + (size_t)blockIdx.y * gridDim.x + blockIdx.x] = sred[0];
}

__global__ __launch_bounds__(256) void k_mean(const float* __restrict__ partials,
                                              float* __restrict__ means)
{
    int b = blockIdx.x;
    int t = threadIdx.x;
    float s = partials[(size_t)b * 1024 + t]
            + partials[(size_t)b * 1024 + t + 256]
            + partials[(size_t)b * 1024 + t + 512]
            + partials[(size_t)b * 1024 + t + 768];
    __shared__ float sr[256];
    sr[t] = s;
    __syncthreads();
    for (int off = 128; off > 0; off >>= 1) {
        if (t < off) sr[t] += sr[t + off];
        __syncthreads();
    }
    if (t == 0) means[b] = sr[0] * (1.f / (float)PLANE);
}

__global__ __launch_bounds__(256) void k_jitter(float* __restrict__ oimgs,
                                                const float* __restrict__ means,
                                                const float* __restrict__ contrast,
                                                const float* __restrict__ saturation,
                                                const float* __restrict__ hue)
{
    int x = blockIdx.x * 32 + threadIdx.x;
    int y = blockIdx.y * 8 + threadIdx.y;
    int b = blockIdx.z;
    size_t po = (size_t)b * 3 * PLANE + (size_t)y * Wd + x;
    float r = oimgs[po];
    float g = oimgs[po + PLANE];
    float bl = oimgs[po + 2 * PLANE];

    float mean = means[b];
    float cf = contrast[b];
    float sf = saturation[b];
    float hshift = hue[b];

    r = clip01(cf * r + (1.f - cf) * mean);
    g = clip01(cf * g + (1.f - cf) * mean);
    bl = clip01(cf * bl + (1.f - cf) * mean);

    float gray = 0.299f * r + 0.587f * g + 0.114f * bl;
    r = clip01(sf * r + (1.f - sf) * gray);
    g = clip01(sf * g + (1.f - sf) * gray);
    bl = clip01(sf * bl + (1.f - sf) * gray);

    float maxc = fmaxf(fmaxf(r, g), bl);
    float minc = fminf(fminf(r, g), bl);
    float delta = maxc - minc;
    float s = delta / (maxc + 1e-8f);
    float dd = delta + 1e-8f;
    float rc = (maxc - r) / dd;
    float gc = (maxc - g) / dd;
    float bc = (maxc - bl) / dd;
    float h6 = (maxc == r) ? (bc - gc) : ((maxc == g) ? (2.f + rc - bc) : (4.f + gc - rc));
    float h = h6 * (1.f / 6.f);
    h = h - floorf(h);
    h = h + hshift;
    h = h - floorf(h);

    float hi = floorf(h * 6.f);
    float f = h * 6.f - hi;
    float v = maxc;
    float p = v * (1.f - s);
    float q = v * (1.f - f * s);
    float t = v * (1.f - (1.f - f) * s);
    int i = ((int)hi) % 6;
    if (i < 0) i += 6;
    float rr, gg, bb;
    switch (i) {
        case 0: rr = v; gg = t; bb = p; break;
        case 1: rr = q; gg = v; bb = p; break;
        case 2: rr = p; gg = v; bb = t; break;
        case 3: rr = p; gg = q; bb = v; break;
        case 4: rr = t; gg = p; bb = v; break;
        default: rr = v; gg = p; bb = q; break;
    }

    oimgs[po] = clip01(rr);
    oimgs[po + PLANE] = clip01(gg);
    oimgs[po + 2 * PLANE] = clip01(bb);
}

extern "C" void kernel_launch(void* const* d_in, const int* in_sizes, int n_in,
                              void* d_out, int out_size, void* d_ws, size_t ws_size,
                              hipStream_t stream)
{
    const float* imgs       = (const float*)d_in[0];
    const float* masks      = (const float*)d_in[1];
    const int*   hflip      = (const int*)d_in[2];
    const int*   vflip      = (const int*)d_in[3];
    const float* angles     = (const float*)d_in[4];
    const float* translate  = (const float*)d_in[5];
    const float* scale      = (const float*)d_in[6];
    const float* brightness = (const float*)d_in[7];
    const float* contrast   = (const float*)d_in[8];
    const float* saturation = (const float*)d_in[9];
    const float* hue        = (const float*)d_in[10];

    float* oimgs  = (float*)d_out;
    float* omasks = oimgs + (size_t)Bd * 3 * PLANE;

    float* ws       = (float*)d_ws;
    float* rimgs    = ws;
    float* rmasks   = rimgs + (size_t)Bd * 3 * PLANE;
    float* partials = rmasks + (size_t)Bd * PLANE;
    float* means    = partials + Bd * 1024;

    dim3 blk(32, 8);
    dim3 grd(Wd / 32, Hd / 8, Bd);

    k_rotate<<<grd, blk, 0, stream>>>(imgs, masks, hflip, vflip, angles, rimgs, rmasks);
    k_affine<<<grd, blk, 0, stream>>>(rimgs, rmasks, translate, scale, brightness,
                                      oimgs, omasks, partials);
    k_mean<<<Bd, 256, 0, stream>>>(partials, means);
    k_jitter<<<grd, blk, 0, stream>>>(oimgs, means, contrast, saturation, hue);
}

// Round 3
// 202.485 us; speedup vs baseline: 1.2885x; 1.0166x over previous
//
#include <hip/hip_runtime.h>
#include <math.h>

#define Wd 512
#define Hd 512
#define Bd 32
#define PLANE (Hd * Wd)

// LDS patches for the fused rotate+affine kernel (32x8 output tile):
//  - rot patch (intermediate rotated image cells): worst 39x12  -> 40x12
//  - orig patch (rotate source bbox of the rot patch): worst 44x44
#define RPW 40
#define RPH 12
#define OPW 44
#define OPH 44

__device__ __forceinline__ float clip01(float x) { return fminf(fmaxf(x, 0.f), 1.f); }

// ---------------------------------------------------------------------------
// K1: flip + rotate + affine + brightness, fused. Two-stage resample entirely
// in LDS: stage original bbox (zero-padded, flips folded into gather index),
// compute rotated patch on integer grid (zero outside image = reference
// validity), affine-sample the rotated patch. Masks go straight to d_out;
// pre-jitter imgs go to d_out (jitter is a later in-place pass); per-block
// gray partial sums for the contrast mean.
// ---------------------------------------------------------------------------
__global__ __launch_bounds__(256) void k_rotaffine(const float* __restrict__ imgs,
                                                   const float* __restrict__ masks,
                                                   const int* __restrict__ hflip,
                                                   const int* __restrict__ vflip,
                                                   const float* __restrict__ angles,
                                                   const float* __restrict__ translate,
                                                   const float* __restrict__ scale,
                                                   const float* __restrict__ brightness,
                                                   float* __restrict__ oimgs,
                                                   float* __restrict__ omasks,
                                                   float* __restrict__ partials)
{
    __shared__ float4 opatch[OPH * OPW];   // 30976 B
    __shared__ float4 rpatch[RPH * RPW];   // 7680 B (aliased as reduce scratch later)

    const int tx = threadIdx.x, ty = threadIdx.y;
    const int bx = blockIdx.x * 32, by = blockIdx.y * 8;
    const int b = blockIdx.z;

    const float cx = (Wd - 1) * 0.5f, cy = (Hd - 1) * 0.5f;
    const float th = angles[b] * 0.017453292519943295f;
    const float c = cosf(th), s = sinf(th);
    const bool hf = hflip[b] > 0, vf = vflip[b] > 0;
    const float txf = translate[2 * b] * (float)Wd;
    const float tyf = translate[2 * b + 1] * (float)Hd;
    const float sc = scale[b];
    const float bf = brightness[b];

    // ---- affine source bbox (in rotated-image coords) for this 32x8 tile ----
    // corner formulas are bit-identical to the per-pixel formula (monotone in x,y)
    float ax0 = ((float)bx - cx - txf) / sc + cx;
    float ax1 = ((float)(bx + 31) - cx - txf) / sc + cx;
    float ay0 = ((float)by - cy - tyf) / sc + cy;
    float ay1 = ((float)(by + 7) - cy - tyf) / sc + cy;
    int rx0 = (int)floorf(fminf(ax0, ax1)) - 1;
    int ry0 = (int)floorf(fminf(ay0, ay1)) - 1;
    int bwr = min((int)floorf(fmaxf(ax0, ax1)) + 2 - rx0 + 1, RPW);
    int bhr = min((int)floorf(fmaxf(ay0, ay1)) + 2 - ry0 + 1, RPH);

    // ---- rotate source bbox (in original coords) for the rot patch ----
    float rdx0 = (float)rx0 - cx, rdx1 = (float)(rx0 + bwr - 1) - cx;
    float rdy0 = (float)ry0 - cy, rdy1 = (float)(ry0 + bhr - 1) - cy;
    float sx00 = c * rdx0 + s * rdy0, sx10 = c * rdx1 + s * rdy0;
    float sx01 = c * rdx0 + s * rdy1, sx11 = c * rdx1 + s * rdy1;
    float sy00 = -s * rdx0 + c * rdy0, sy10 = -s * rdx1 + c * rdy0;
    float sy01 = -s * rdx0 + c * rdy1, sy11 = -s * rdx1 + c * rdy1;
    float minsx = fminf(fminf(sx00, sx10), fminf(sx01, sx11)) + cx;
    float maxsx = fmaxf(fmaxf(sx00, sx10), fmaxf(sx01, sx11)) + cx;
    float minsy = fminf(fminf(sy00, sy10), fminf(sy01, sy11)) + cy;
    float maxsy = fmaxf(fmaxf(sy00, sy10), fmaxf(sy01, sy11)) + cy;
    int ox0 = (int)floorf(minsx) - 1;
    int oy0 = (int)floorf(minsy) - 1;
    int obw = min((int)floorf(maxsx) + 2 - ox0 + 1, OPW);
    int obh = min((int)floorf(maxsy) + 2 - oy0 + 1, OPH);

    const float* ib = imgs + (size_t)b * 3 * PLANE;
    const float* mb = masks + (size_t)b * PLANE;

    // ---- stage original patch (coalesced rows; zero outside; flip folded) ----
    for (int row = ty; row < obh; row += 8) {
        int gy = oy0 + row;
        int fy = vf ? (Hd - 1 - gy) : gy;
        bool yin = (unsigned)gy < (unsigned)Hd;
        for (int col = tx; col < obw; col += 32) {
            int gx = ox0 + col;
            float4 v = make_float4(0.f, 0.f, 0.f, 0.f);
            if (yin && (unsigned)gx < (unsigned)Wd) {
                int fx = hf ? (Wd - 1 - gx) : gx;
                int gi = fy * Wd + fx;
                v.x = ib[gi];
                v.y = ib[gi + PLANE];
                v.z = ib[gi + 2 * PLANE];
                v.w = mb[gi];
            }
            opatch[row * OPW + col] = v;
        }
    }
    __syncthreads();

    // ---- compute rotated patch on its integer grid ----
    for (int j = ty; j < bhr; j += 8) {
        int gy = ry0 + j;
        float dyy = (float)gy - cy;
        for (int i = tx; i < bwr; i += 32) {
            int gx = rx0 + i;
            float4 v = make_float4(0.f, 0.f, 0.f, 0.f);
            if ((unsigned)gx < (unsigned)Wd && (unsigned)gy < (unsigned)Hd) {
                float dxx = (float)gx - cx;
                float sx = c * dxx + s * dyy + cx;
                float sy = -s * dxx + c * dyy + cy;
                float sxl = sx - (float)ox0;
                float syl = sy - (float)oy0;
                float x0f = floorf(sxl), y0f = floorf(syl);
                float wx = sxl - x0f, wy = syl - y0f;
                int xi = min(max((int)x0f, 0), obw - 2);
                int yi = min(max((int)y0f, 0), obh - 2);
                const float4* p = &opatch[yi * OPW + xi];
                float4 v00 = p[0], v10 = p[1], v01 = p[OPW], v11 = p[OPW + 1];
                float w00 = (1.f - wx) * (1.f - wy);
                float w10 = wx * (1.f - wy);
                float w01 = (1.f - wx) * wy;
                float w11 = wx * wy;
                v.x = w00 * v00.x + w10 * v10.x + w01 * v01.x + w11 * v11.x;
                v.y = w00 * v00.y + w10 * v10.y + w01 * v01.y + w11 * v11.y;
                v.z = w00 * v00.z + w10 * v10.z + w01 * v01.z + w11 * v11.z;
                v.w = w00 * v00.w + w10 * v10.w + w01 * v01.w + w11 * v11.w;
            }
            rpatch[j * RPW + i] = v;
        }
    }
    __syncthreads();

    // ---- affine sample from rotated patch ----
    int x = bx + tx, y = by + ty;
    float sx = ((float)x - cx - txf) / sc + cx;
    float sy = ((float)y - cy - tyf) / sc + cy;
    float sxl = sx - (float)rx0;
    float syl = sy - (float)ry0;
    float x0f = floorf(sxl), y0f = floorf(syl);
    float wx = sxl - x0f, wy = syl - y0f;
    int xi = min(max((int)x0f, 0), bwr - 2);
    int yi = min(max((int)y0f, 0), bhr - 2);
    const float4* p = &rpatch[yi * RPW + xi];
    float4 v00 = p[0], v10 = p[1], v01 = p[RPW], v11 = p[RPW + 1];
    float w00 = (1.f - wx) * (1.f - wy);
    float w10 = wx * (1.f - wy);
    float w01 = (1.f - wx) * wy;
    float w11 = wx * wy;

    float r  = w00 * v00.x + w10 * v10.x + w01 * v01.x + w11 * v11.x;
    float g  = w00 * v00.y + w10 * v10.y + w01 * v01.y + w11 * v11.y;
    float b2 = w00 * v00.z + w10 * v10.z + w01 * v01.z + w11 * v11.z;
    float m  = w00 * v00.w + w10 * v10.w + w01 * v01.w + w11 * v11.w;

    r = clip01(r * bf);
    g = clip01(g * bf);
    b2 = clip01(b2 * bf);

    size_t po = (size_t)b * 3 * PLANE + (size_t)y * Wd + x;
    oimgs[po] = r;
    oimgs[po + PLANE] = g;
    oimgs[po + 2 * PLANE] = b2;
    omasks[(size_t)b * PLANE + (size_t)y * Wd + x] = m;

    // ---- per-block reduction of post-brightness gray (rpatch reused) ----
    float gray = 0.299f * r + 0.587f * g + 0.114f * b2;
    __syncthreads();                       // all rpatch reads done
    float* sred = reinterpret_cast<float*>(rpatch);
    int tid = ty * 32 + tx;
    sred[tid] = gray;
    __syncthreads();
    for (int off = 128; off > 0; off >>= 1) {
        if (tid < off) sred[tid] += sred[tid + off];
        __syncthreads();
    }
    if (tid == 0)
        partials[(size_t)b * 1024 + (size_t)blockIdx.y * gridDim.x + blockIdx.x] = sred[0];
}

__global__ __launch_bounds__(256) void k_mean(const float* __restrict__ partials,
                                              float* __restrict__ means)
{
    int b = blockIdx.x;
    int t = threadIdx.x;
    float s = partials[(size_t)b * 1024 + t]
            + partials[(size_t)b * 1024 + t + 256]
            + partials[(size_t)b * 1024 + t + 512]
            + partials[(size_t)b * 1024 + t + 768];
    __shared__ float sr[256];
    sr[t] = s;
    __syncthreads();
    for (int off = 128; off > 0; off >>= 1) {
        if (t < off) sr[t] += sr[t + off];
        __syncthreads();
    }
    if (t == 0) means[b] = sr[0] * (1.f / (float)PLANE);
}

__global__ __launch_bounds__(256) void k_jitter(float* __restrict__ oimgs,
                                                const float* __restrict__ means,
                                                const float* __restrict__ contrast,
                                                const float* __restrict__ saturation,
                                                const float* __restrict__ hue)
{
    int x = blockIdx.x * 32 + threadIdx.x;
    int y = blockIdx.y * 8 + threadIdx.y;
    int b = blockIdx.z;
    size_t po = (size_t)b * 3 * PLANE + (size_t)y * Wd + x;
    float r = oimgs[po];
    float g = oimgs[po + PLANE];
    float bl = oimgs[po + 2 * PLANE];

    float mean = means[b];
    float cf = contrast[b];
    float sf = saturation[b];
    float hshift = hue[b];

    r = clip01(cf * r + (1.f - cf) * mean);
    g = clip01(cf * g + (1.f - cf) * mean);
    bl = clip01(cf * bl + (1.f - cf) * mean);

    float gray = 0.299f * r + 0.587f * g + 0.114f * bl;
    r = clip01(sf * r + (1.f - sf) * gray);
    g = clip01(sf * g + (1.f - sf) * gray);
    bl = clip01(sf * bl + (1.f - sf) * gray);

    float maxc = fmaxf(fmaxf(r, g), bl);
    float minc = fminf(fminf(r, g), bl);
    float delta = maxc - minc;
    float sgm = delta / (maxc + 1e-8f);
    float dd = delta + 1e-8f;
    float rc = (maxc - r) / dd;
    float gc = (maxc - g) / dd;
    float bc = (maxc - bl) / dd;
    float h6 = (maxc == r) ? (bc - gc) : ((maxc == g) ? (2.f + rc - bc) : (4.f + gc - rc));
    float h = h6 * (1.f / 6.f);
    h = h - floorf(h);
    h = h + hshift;
    h = h - floorf(h);

    float hi = floorf(h * 6.f);
    float f = h * 6.f - hi;
    float v = maxc;
    float pq = v * (1.f - sgm);
    float q = v * (1.f - f * sgm);
    float t = v * (1.f - (1.f - f) * sgm);
    int i = ((int)hi) % 6;
    if (i < 0) i += 6;
    float rr, gg, bb;
    switch (i) {
        case 0: rr = v;  gg = t;  bb = pq; break;
        case 1: rr = q;  gg = v;  bb = pq; break;
        case 2: rr = pq; gg = v;  bb = t;  break;
        case 3: rr = pq; gg = q;  bb = v;  break;
        case 4: rr = t;  gg = pq; bb = v;  break;
        default: rr = v; gg = pq; bb = q;  break;
    }

    oimgs[po] = clip01(rr);
    oimgs[po + PLANE] = clip01(gg);
    oimgs[po + 2 * PLANE] = clip01(bb);
}

extern "C" void kernel_launch(void* const* d_in, const int* in_sizes, int n_in,
                              void* d_out, int out_size, void* d_ws, size_t ws_size,
                              hipStream_t stream)
{
    const float* imgs       = (const float*)d_in[0];
    const float* masks      = (const float*)d_in[1];
    const int*   hflip      = (const int*)d_in[2];
    const int*   vflip      = (const int*)d_in[3];
    const float* angles     = (const float*)d_in[4];
    const float* translate  = (const float*)d_in[5];
    const float* scale      = (const float*)d_in[6];
    const float* brightness = (const float*)d_in[7];
    const float* contrast   = (const float*)d_in[8];
    const float* saturation = (const float*)d_in[9];
    const float* hue        = (const float*)d_in[10];

    float* oimgs  = (float*)d_out;
    float* omasks = oimgs + (size_t)Bd * 3 * PLANE;

    float* partials = (float*)d_ws;          // 32*1024
    float* means    = partials + Bd * 1024;  // 32

    dim3 blk(32, 8);
    dim3 grd(Wd / 32, Hd / 8, Bd);

    k_rotaffine<<<grd, blk, 0, stream>>>(imgs, masks, hflip, vflip, angles,
                                         translate, scale, brightness,
                                         oimgs, omasks, partials);
    k_mean<<<Bd, 256, 0, stream>>>(partials, means);
    k_jitter<<<grd, blk, 0, stream>>>(oimgs, means, contrast, saturation, hue);
}